// Round 16
// baseline (179.072 us; speedup 1.0000x reference)
//
#include <hip/hip_runtime.h>
#include <math.h>

#define NN 10000
#define NE 160000

typedef __attribute__((ext_vector_type(8))) short s8v;
typedef __attribute__((ext_vector_type(4))) float f4v;
typedef unsigned short u16;

// ---- ws byte layout ----
#define OFF_P1HB 0u          // N*32 bf16      = 640000 B
#define OFF_P3HB 640000u     // N*3*32 bf16    = 1920000 B
#define OFF_WB   2560000u    // NWB u16        = 143360 B
#define OFF_SCR  2703360u    // 8320 f32 scratch (T1,T3,bt1,bt3) = 33280 B
#define OFF_P1N  2736640u    // N*32 f32       = 1280000 B
#define OFF_P3N  4016640u    // N*3*32 f32     = 3840000 B

// ---- wb (u16) offsets: fused weights, lane-consumption order [..][64][8] --
#define OWF1  0       // [b8][nt6][ks2][64][8] = 49152  (Wf1 = W1@W2@W3)
#define OBB1  49152   // [nt6][64][8]          = 3072   (bf1, k<8 else 0)
#define OII1T 52224   // [nt2][64][8]          = 1024
#define OWF3  53248   // [b8][nt2][ks2][64][8] = 16384  (Wf3 = W13@W23@W33)
#define OBB3  69632   // [nt2][64][8]          = 1024   (bf3)
#define OII3T 70656   // [nt2][64][8]          = 1024
#define NWB   71680

__device__ __forceinline__ short f2b(float f) {
    unsigned u = __float_as_uint(f);
    u += 0x7fffu + ((u >> 16) & 1u);
    return (short)(u >> 16);
}
__device__ __forceinline__ float tanhf_fast(float x) {
    float xc = fminf(9.f, fmaxf(-9.f, x));
    float e = __expf(2.f * xc);
    return (e - 1.f) * __builtin_amdgcn_rcpf(e + 1.f);
}

// ---------------- node prep: p1h/p3h = tanh(x@W+b) -> bf16 ----------------
__global__ __launch_bounds__(256) void node_prep(
    const float* __restrict__ p1, const float* __restrict__ p3,
    const float* __restrict__ pp1_W, const float* __restrict__ pp1_b,
    const float* __restrict__ pp3_W, const float* __restrict__ pp3_b,
    u16* __restrict__ p1hb, u16* __restrict__ p3hb)
{
    __shared__ float Ws[2][32 * 32];
    __shared__ float bsm[2][32];
    int tid = threadIdx.x;
    for (int i = tid; i < 32 * 32; i += 256) { Ws[0][i] = pp1_W[i]; Ws[1][i] = pp3_W[i]; }
    if (tid < 32) { bsm[0][tid] = pp1_b[tid]; bsm[1][tid] = pp3_b[tid]; }
    __syncthreads();
    int idx = blockIdx.x * 256 + tid;
    int n = idx >> 7;
    int r = (idx >> 5) & 3;
    int c = idx & 31;
    int sel = (r == 0) ? 0 : 1;
    const float* in = (r == 0) ? (p1 + n * 32) : (p3 + (n * 3 + (r - 1)) * 32);
    float acc = bsm[sel][c];
    #pragma unroll
    for (int k = 0; k < 32; ++k) acc += in[k] * Ws[sel][k * 32 + c];
    short v = f2b(tanhf(acc));
    if (r == 0) p1hb[n * 32 + c] = (u16)v;
    else        p3hb[(n * 3 + (r - 1)) * 32 + c] = (u16)v;
}

// ---- wprep stage 1: T1 = W1@W2 [64][96], T3 = W13@W23 [64][32],
//      bt1 = b1@W2 + b2 [96], bt3 = b13@W23 + b23 [32]  (all f32) ----------
__global__ __launch_bounds__(256) void wprep1(
    const float* __restrict__ W1, const float* __restrict__ W2,
    const float* __restrict__ b1, const float* __restrict__ b2,
    const float* __restrict__ W13, const float* __restrict__ W23,
    const float* __restrict__ b13, const float* __restrict__ b23,
    float* __restrict__ scr)
{
    float* T1  = scr;            // [64][96]
    float* T3  = scr + 6144;     // [64][32]
    float* bt1 = scr + 8192;     // [96]
    float* bt3 = scr + 8288;     // [32]
    int i = blockIdx.x * 256 + threadIdx.x;
    if (i < 6144) {
        int r = i / 96, c = i % 96;
        float a = 0.f;
        #pragma unroll 8
        for (int k = 0; k < 32; ++k) a += W1[r * 32 + k] * W2[k * 96 + c];
        T1[i] = a;
    } else if ((i -= 6144) < 2048) {
        int r = i / 32, c = i % 32;
        float a = 0.f;
        #pragma unroll 8
        for (int k = 0; k < 32; ++k) a += W13[r * 32 + k] * W23[k * 32 + c];
        T3[i] = a;
    } else if ((i -= 2048) < 96) {
        float a = b2[i];
        #pragma unroll 8
        for (int k = 0; k < 32; ++k) a += b1[k] * W2[k * 96 + i];
        bt1[i] = a;
    } else if ((i -= 96) < 32) {
        float a = b23[i];
        #pragma unroll 8
        for (int k = 0; k < 32; ++k) a += b13[k] * W23[k * 32 + i];
        bt3[i] = a;
    }
}

// ---- wprep stage 2: fused bf16 tables; T1/T3/bt staged in LDS per block --
__global__ __launch_bounds__(256) void wprep2(
    const float* __restrict__ W3, const float* __restrict__ W33,
    const float* __restrict__ ii1, const float* __restrict__ ii3,
    const float* __restrict__ scr, u16* __restrict__ wb)
{
    __shared__ float sT1[6144];   // 24576 B
    __shared__ float sT3[2048];   // 8192 B
    __shared__ float sbt[128];    // bt1[96] | bt3[32]
    int tid = threadIdx.x;
    for (int i = tid; i < 6144; i += 256) sT1[i] = scr[i];
    for (int i = tid; i < 2048; i += 256) sT3[i] = scr[6144 + i];
    if (tid < 128) sbt[tid] = scr[8192 + tid];
    __syncthreads();

    int i0 = blockIdx.x * 256 + tid;
    if (i0 >= NWB) return;
    int i = i0;
    float v = 0.f;
    if (i < 49152) {            // WF1[b][nt][ks][L][j] = Wf1[k][c*8+b]
        int b = i / 6144, r = i % 6144;
        int nt = r / 1024, r2 = r % 1024;
        int ks = r2 / 512, r3 = r2 & 511;
        int L = r3 >> 3, j = r3 & 7;
        int k = ks * 32 + (L >> 4) * 8 + j;
        int c = 16 * nt + (L & 15);
        float a = 0.f;
        #pragma unroll 8
        for (int q = 0; q < 96; ++q) a += sT1[k * 96 + q] * W3[q * 768 + c * 8 + b];
        v = a;
    } else if ((i -= 49152) < 3072) {   // BB1[nt][L][j]
        int nt = i / 512, r3 = i & 511;
        int L = r3 >> 3, j = r3 & 7;
        if ((L >> 4) == 0) {
            int x = (16 * nt + (L & 15)) * 8 + j;
            float a = 0.f;
            #pragma unroll 8
            for (int q = 0; q < 96; ++q) a += sbt[q] * W3[q * 768 + x];
            v = a;
        }
    } else if ((i -= 3072) < 1024) {    // II1T[nt][L][j]
        int nt = i / 512, r3 = i & 511;
        int L = r3 >> 3, j = r3 & 7;
        v = ii1[((L >> 4) * 8 + j) * 32 + 16 * nt + (L & 15)];
    } else if ((i -= 1024) < 16384) {   // WF3[b][nt][ks][L][j]
        int b = i / 2048, r = i % 2048;
        int nt = r / 1024, r2 = r % 1024;
        int ks = r2 / 512, r3 = r2 & 511;
        int L = r3 >> 3, j = r3 & 7;
        int k = ks * 32 + (L >> 4) * 8 + j;
        int c = 16 * nt + (L & 15);
        float a = 0.f;
        #pragma unroll 8
        for (int q = 0; q < 32; ++q) a += sT3[k * 32 + q] * W33[q * 256 + c * 8 + b];
        v = a;
    } else if ((i -= 16384) < 1024) {   // BB3[nt][L][j]
        int nt = i / 512, r3 = i & 511;
        int L = r3 >> 3, j = r3 & 7;
        if ((L >> 4) == 0) {
            int x = (16 * nt + (L & 15)) * 8 + j;
            float a = 0.f;
            #pragma unroll 8
            for (int q = 0; q < 32; ++q) a += sbt[96 + q] * W33[q * 256 + x];
            v = a;
        }
    } else {                            // II3T[nt][L][j]
        i -= 1024;
        int nt = i / 512, r3 = i & 511;
        int L = r3 >> 3, j = r3 & 7;
        v = ii3[((L >> 4) * 8 + j) * 32 + 16 * nt + (L & 15)];
    }
    wb[i0] = (u16)f2b(v);
}

// ------- fused edge kernel: 32 edges per 1-wave block (2 M-tiles) ---------
// (64,4): VGPR cap 128 vs ~112 needed -> 4 resident waves/SIMD (was 3 cap,
// 2.1 observed). Per-transpose LDS slots kill WAR stalls; pi3 gathers are
// software-pipelined one d ahead (T14).
__global__ __launch_bounds__(64, 4) void edge_kernel(
    const u16* __restrict__ p1hb, const u16* __restrict__ p3hb,
    const float* __restrict__ r3, const float* __restrict__ basis,
    const int* __restrict__ idx_i, const int* __restrict__ idx_j,
    const u16* __restrict__ wb,
    const float* __restrict__ ii1b, const float* __restrict__ ii3b,
    float* __restrict__ p1n, float* __restrict__ p3n)
{
    // 11904 B LDS, single wave per block
    __shared__ int4 smem4[744];
    char* sw = (char*)smem4;
    int*   sIdxI = (int*)(sw + 0);       // [32]
    int*   sIdxJ = (int*)(sw + 128);     // [32]
    float* sBasT = (float*)(sw + 256);   // [8][32] transposed basis
    float* sR3   = (float*)(sw + 1280);  // [3][32]
    u16*   sT2   = (u16*)(sw + 1664);    // [8 slots][16][40] transpose buffers

    const int l   = threadIdx.x & 63;
    const int r16 = l & 15;
    const int kg  = l >> 4;
    const int ebase = blockIdx.x * 32;

    // ---- staging (single wave: in-order LDS, no barriers) ----
    if (l < 32) sIdxI[l] = idx_i[ebase + l];
    else        sIdxJ[l - 32] = idx_j[ebase + l - 32];
    {
        int e = l & 31, hf = l >> 5;
        const float4* bp = (const float4*)(basis + (size_t)(ebase + e) * 8);
        float4 q = bp[hf];
        sBasT[(4 * hf + 0) * 32 + e] = q.x;
        sBasT[(4 * hf + 1) * 32 + e] = q.y;
        sBasT[(4 * hf + 2) * 32 + e] = q.z;
        sBasT[(4 * hf + 3) * 32 + e] = q.w;
        if (hf == 0) {
            sR3[e]      = r3[(size_t)(ebase + e) * 3 + 0];
            sR3[32 + e] = r3[(size_t)(ebase + e) * 3 + 1];
            sR3[64 + e] = r3[(size_t)(ebase + e) * 3 + 2];
        }
    }

    const float vii1[2] = { ii1b[r16], ii1b[16 + r16] };
    const float vii3[2] = { ii3b[r16], ii3b[16 + r16] };

    const f4v zf = {0.f, 0.f, 0.f, 0.f};

    // basis as K=8-padded A-fragment (for bias-init MFMAs)
    s8v bA[2];
    #pragma unroll
    for (int m = 0; m < 2; ++m) {
        s8v t;
        #pragma unroll
        for (int j = 0; j < 8; ++j)
            t[j] = (kg == 0) ? f2b(sBasT[j * 32 + m * 16 + r16]) : (short)0;
        bA[m] = t;
    }

    // ---- pi1: inter gathers (A-frags) ----
    s8v avI[2], avJ[2];
    #pragma unroll
    for (int m = 0; m < 2; ++m) {
        int rowA = m * 16 + r16;
        avI[m] = *(const s8v*)(p1hb + (size_t)sIdxI[rowA] * 32 + kg * 8);
        avJ[m] = *(const s8v*)(p1hb + (size_t)sIdxJ[rowA] * 32 + kg * 8);
    }

    // accT init = basis @ bf1  (bias term)
    f4v accT[2][6];
    {
        const u16* gBB = wb + OBB1;
        #pragma unroll
        for (int nt = 0; nt < 6; ++nt) {
            s8v bbv = *(const s8v*)(gBB + (nt * 64 + l) * 8);
            #pragma unroll
            for (int m = 0; m < 2; ++m)
                accT[m][nt] = __builtin_amdgcn_mfma_f32_16x16x32_bf16(bA[m], bbv, zf, 0, 0, 0);
        }
    }

    // ---- pi1 main: accT += basis_b * (inter @ Wf1_b) ----
    {
        const u16* gW = wb + OWF1;
        #pragma unroll 2
        for (int b = 0; b < 8; ++b) {
            float tb[2][4];
            #pragma unroll
            for (int m = 0; m < 2; ++m)
                #pragma unroll
                for (int rr = 0; rr < 4; ++rr)
                    tb[m][rr] = sBasT[b * 32 + m * 16 + 4 * kg + rr];
            #pragma unroll
            for (int nt = 0; nt < 6; ++nt) {
                const u16* bp = gW + ((size_t)(b * 6 + nt) * 2) * 512 + l * 8;
                s8v bv0 = *(const s8v*)(bp);
                s8v bv1 = *(const s8v*)(bp + 512);
                #pragma unroll
                for (int m = 0; m < 2; ++m) {
                    f4v D = __builtin_amdgcn_mfma_f32_16x16x32_bf16(avI[m], bv0, zf, 0, 0, 0);
                    D = __builtin_amdgcn_mfma_f32_16x16x32_bf16(avJ[m], bv1, D, 0, 0, 0);
                    #pragma unroll
                    for (int rr = 0; rr < 4; ++rr)
                        accT[m][nt][rr] += tb[m][rr] * D[rr];
                }
            }
        }
    }

    // ---- ii1: tanh(i1_1 @ ii1_W + b) -> atomic p1n[idx_j] ----
    {
        const u16* gII = wb + OII1T;
        #pragma unroll
        for (int m = 0; m < 2; ++m) {
            u16* T2 = sT2 + m * 640;            // per-m slot (no WAR stall)
            #pragma unroll
            for (int nt = 0; nt < 2; ++nt)
                #pragma unroll
                for (int rr = 0; rr < 4; ++rr)
                    T2[(4 * kg + rr) * 40 + 16 * nt + r16] = (u16)f2b(accT[m][nt][rr]);
            s8v av = *(const s8v*)(T2 + r16 * 40 + 8 * kg);
            #pragma unroll
            for (int nt = 0; nt < 2; ++nt) {
                s8v bv = *(const s8v*)(gII + (nt * 64 + l) * 8);
                f4v ia = __builtin_amdgcn_mfma_f32_16x16x32_bf16(av, bv, zf, 0, 0, 0);
                #pragma unroll
                for (int rr = 0; rr < 4; ++rr) {
                    int rowD = m * 16 + 4 * kg + rr;
                    atomicAdd(&p1n[(size_t)sIdxJ[rowD] * 32 + 16 * nt + r16],
                              tanhf_fast(ia[rr] + vii1[nt]));
                }
            }
        }
    }

    // ---- pi3 branch per Cartesian d (gathers pipelined one d ahead) ----
    const u16* gW3  = wb + OWF3;
    const u16* gBB3 = wb + OBB3;
    const u16* gII3 = wb + OII3T;
    s8v nI3[2], nJ3[2];
    #pragma unroll
    for (int m = 0; m < 2; ++m) {
        int rowA = m * 16 + r16;
        nI3[m] = *(const s8v*)(p3hb + ((size_t)sIdxI[rowA] * 3 + 0) * 32 + kg * 8);
        nJ3[m] = *(const s8v*)(p3hb + ((size_t)sIdxJ[rowA] * 3 + 0) * 32 + kg * 8);
    }
    #pragma unroll 1
    for (int d = 0; d < 3; ++d) {
        s8v avI3[2], avJ3[2];
        avI3[0] = nI3[0]; avI3[1] = nI3[1];
        avJ3[0] = nJ3[0]; avJ3[1] = nJ3[1];
        if (d < 2) {
            #pragma unroll
            for (int m = 0; m < 2; ++m) {
                int rowA = m * 16 + r16;
                nI3[m] = *(const s8v*)(p3hb + ((size_t)sIdxI[rowA] * 3 + d + 1) * 32 + kg * 8);
                nJ3[m] = *(const s8v*)(p3hb + ((size_t)sIdxJ[rowA] * 3 + d + 1) * 32 + kg * 8);
            }
        }
        f4v accP[2][2];
        #pragma unroll
        for (int nt = 0; nt < 2; ++nt) {
            s8v bbv = *(const s8v*)(gBB3 + (nt * 64 + l) * 8);
            #pragma unroll
            for (int m = 0; m < 2; ++m)
                accP[m][nt] = __builtin_amdgcn_mfma_f32_16x16x32_bf16(bA[m], bbv, zf, 0, 0, 0);
        }
        #pragma unroll 2
        for (int b = 0; b < 8; ++b) {
            float tb[2][4];
            #pragma unroll
            for (int m = 0; m < 2; ++m)
                #pragma unroll
                for (int rr = 0; rr < 4; ++rr)
                    tb[m][rr] = sBasT[b * 32 + m * 16 + 4 * kg + rr];
            #pragma unroll
            for (int nt = 0; nt < 2; ++nt) {
                const u16* bp = gW3 + ((size_t)(b * 2 + nt) * 2) * 512 + l * 8;
                s8v bv0 = *(const s8v*)(bp);
                s8v bv1 = *(const s8v*)(bp + 512);
                #pragma unroll
                for (int m = 0; m < 2; ++m) {
                    f4v D = __builtin_amdgcn_mfma_f32_16x16x32_bf16(avI3[m], bv0, zf, 0, 0, 0);
                    D = __builtin_amdgcn_mfma_f32_16x16x32_bf16(avJ3[m], bv1, D, 0, 0, 0);
                    #pragma unroll
                    for (int rr = 0; rr < 4; ++rr)
                        accP[m][nt][rr] += tb[m][rr] * D[rr];
                }
            }
        }
        // ii3 + combine + atomic p3n
        #pragma unroll
        for (int m = 0; m < 2; ++m) {
            u16* T2 = sT2 + (2 + d * 2 + m) * 640;   // per-(d,m) slot
            #pragma unroll
            for (int nt = 0; nt < 2; ++nt)
                #pragma unroll
                for (int rr = 0; rr < 4; ++rr)
                    T2[(4 * kg + rr) * 40 + 16 * nt + r16] = (u16)f2b(accP[m][nt][rr]);
            s8v av = *(const s8v*)(T2 + r16 * 40 + 8 * kg);
            #pragma unroll
            for (int nt = 0; nt < 2; ++nt) {
                s8v bv = *(const s8v*)(gII3 + (nt * 64 + l) * 8);
                f4v ja = __builtin_amdgcn_mfma_f32_16x16x32_bf16(av, bv, zf, 0, 0, 0);
                #pragma unroll
                for (int rr = 0; rr < 4; ++rr) {
                    int rowD = m * 16 + 4 * kg + rr;
                    float i3a = tanhf_fast(ja[rr] + vii3[nt]);
                    float val = i3a * accT[m][2 + nt][rr] + sR3[d * 32 + rowD] * accT[m][4 + nt][rr];
                    atomicAdd(&p3n[((size_t)sIdxJ[rowD] * 3 + d) * 32 + 16 * nt + r16], val);
                }
            }
        }
    }
}

// ---------------- finalize: p1o = sum_d p3n^2 + p1n ; p3o = p3n * p1o -----
__global__ __launch_bounds__(256) void finalize_kernel(
    const float* __restrict__ p1n, const float* __restrict__ p3n,
    float* __restrict__ out)
{
    int t = blockIdx.x * 256 + threadIdx.x;
    int n = t >> 5, c = t & 31;
    float a0 = p3n[(n * 3 + 0) * 32 + c];
    float a1 = p3n[(n * 3 + 1) * 32 + c];
    float a2 = p3n[(n * 3 + 2) * 32 + c];
    float p1o = p1n[t] + a0 * a0 + a1 * a1 + a2 * a2;
    out[t] = p1o;
    float* o3 = out + NN * 32;
    o3[(n * 3 + 0) * 32 + c] = a0 * p1o;
    o3[(n * 3 + 1) * 32 + c] = a1 * p1o;
    o3[(n * 3 + 2) * 32 + c] = a2 * p1o;
}

extern "C" void kernel_launch(void* const* d_in, const int* in_sizes, int n_in,
                              void* d_out, int out_size, void* d_ws, size_t ws_size,
                              hipStream_t stream) {
    const float* p1     = (const float*)d_in[0];
    const float* p3     = (const float*)d_in[1];
    const float* r3     = (const float*)d_in[2];
    const float* basis  = (const float*)d_in[3];
    const int*   idx_i  = (const int*)d_in[4];
    const int*   idx_j  = (const int*)d_in[5];
    const float* pp1_W  = (const float*)d_in[6];
    const float* pp1_b  = (const float*)d_in[7];
    const float* pi1_W1 = (const float*)d_in[8];
    const float* pi1_b1 = (const float*)d_in[9];
    const float* pi1_W2 = (const float*)d_in[10];
    const float* pi1_b2 = (const float*)d_in[11];
    const float* pi1_W3 = (const float*)d_in[12];
    const float* ii1_W  = (const float*)d_in[13];
    const float* ii1_b  = (const float*)d_in[14];
    const float* pp3_W  = (const float*)d_in[15];
    const float* pp3_b  = (const float*)d_in[16];
    const float* pi3_W1 = (const float*)d_in[17];
    const float* pi3_b1 = (const float*)d_in[18];
    const float* pi3_W2 = (const float*)d_in[19];
    const float* pi3_b2 = (const float*)d_in[20];
    const float* pi3_W3 = (const float*)d_in[21];
    const float* ii3_W  = (const float*)d_in[22];
    const float* ii3_b  = (const float*)d_in[23];

    char* ws = (char*)d_ws;
    u16*   p1hb = (u16*)(ws + OFF_P1HB);
    u16*   p3hb = (u16*)(ws + OFF_P3HB);
    u16*   wb   = (u16*)(ws + OFF_WB);
    float* scr  = (float*)(ws + OFF_SCR);
    float* p1n  = (float*)(ws + OFF_P1N);
    float* p3n  = (float*)(ws + OFF_P3N);

    hipMemsetAsync(p1n, 0, 5120000, stream);

    node_prep<<<dim3(5000), dim3(256), 0, stream>>>(p1, p3, pp1_W, pp1_b, pp3_W, pp3_b, p1hb, p3hb);
    wprep1<<<dim3(33), dim3(256), 0, stream>>>(
        pi1_W1, pi1_W2, pi1_b1, pi1_b2, pi3_W1, pi3_W2, pi3_b1, pi3_b2, scr);
    wprep2<<<dim3((NWB + 255) / 256), dim3(256), 0, stream>>>(
        pi1_W3, pi3_W3, ii1_W, ii3_W, scr, wb);

    edge_kernel<<<dim3(NE / 32), dim3(64), 0, stream>>>(
        p1hb, p3hb, r3, basis, idx_i, idx_j, wb,
        ii1_b, ii3_b, p1n, p3n);

    finalize_kernel<<<dim3(1250), dim3(256), 0, stream>>>(p1n, p3n, (float*)d_out);
}

// Round 19
// 139.734 us; speedup vs baseline: 1.2815x; 1.2815x over previous
//
#include <hip/hip_runtime.h>
#include <math.h>

#define NN 10000
#define NE 160000

typedef __attribute__((ext_vector_type(8))) short s8v;
typedef __attribute__((ext_vector_type(4))) float f4v;
typedef unsigned short u16;

// ---- ws byte layout ----
#define OFF_P1HB 0u          // N*32 bf16      = 640000 B
#define OFF_P3HB 640000u     // N*3*32 bf16    = 1920000 B
#define OFF_WB   2560000u    // NWB u16        = 143360 B
#define OFF_SCR  2703360u    // 8320 f32 scratch (T1,T3,bt1,bt3) = 33280 B
#define OFF_P1N  2736640u    // N*32 f32       = 1280000 B
#define OFF_P3N  4016640u    // N*3*32 f32     = 3840000 B

// ---- wb (u16) offsets: fused weights, lane-consumption order [..][64][8] --
#define OWF1  0       // [b8][nt6][ks2][64][8] = 49152  (Wf1 = W1@W2@W3)
#define OBB1  49152   // [nt6][64][8]          = 3072   (bf1, k<8 else 0)
#define OII1T 52224   // [nt2][64][8]          = 1024
#define OWF3  53248   // [b8][nt2][ks2][64][8] = 16384  (Wf3 = W13@W23@W33)
#define OBB3  69632   // [nt2][64][8]          = 1024   (bf3)
#define OII3T 70656   // [nt2][64][8]          = 1024
#define NWB   71680

__device__ __forceinline__ short f2b(float f) {
    unsigned u = __float_as_uint(f);
    u += 0x7fffu + ((u >> 16) & 1u);
    return (short)(u >> 16);
}
__device__ __forceinline__ float tanhf_fast(float x) {
    float xc = fminf(9.f, fmaxf(-9.f, x));
    float e = __expf(2.f * xc);
    return (e - 1.f) * __builtin_amdgcn_rcpf(e + 1.f);
}

// ---------------- node prep: p1h/p3h = tanh(x@W+b) -> bf16 ----------------
__global__ __launch_bounds__(256) void node_prep(
    const float* __restrict__ p1, const float* __restrict__ p3,
    const float* __restrict__ pp1_W, const float* __restrict__ pp1_b,
    const float* __restrict__ pp3_W, const float* __restrict__ pp3_b,
    u16* __restrict__ p1hb, u16* __restrict__ p3hb)
{
    __shared__ float Ws[2][32 * 32];
    __shared__ float bsm[2][32];
    int tid = threadIdx.x;
    for (int i = tid; i < 32 * 32; i += 256) { Ws[0][i] = pp1_W[i]; Ws[1][i] = pp3_W[i]; }
    if (tid < 32) { bsm[0][tid] = pp1_b[tid]; bsm[1][tid] = pp3_b[tid]; }
    __syncthreads();
    int idx = blockIdx.x * 256 + tid;
    int n = idx >> 7;
    int r = (idx >> 5) & 3;
    int c = idx & 31;
    int sel = (r == 0) ? 0 : 1;
    const float* in = (r == 0) ? (p1 + n * 32) : (p3 + (n * 3 + (r - 1)) * 32);
    float acc = bsm[sel][c];
    #pragma unroll
    for (int k = 0; k < 32; ++k) acc += in[k] * Ws[sel][k * 32 + c];
    short v = f2b(tanhf(acc));
    if (r == 0) p1hb[n * 32 + c] = (u16)v;
    else        p3hb[(n * 3 + (r - 1)) * 32 + c] = (u16)v;
}

// ---- wprep stage 1: T1 = W1@W2 [64][96], T3 = W13@W23 [64][32],
//      bt1 = b1@W2 + b2 [96], bt3 = b13@W23 + b23 [32]  (all f32) ----------
__global__ __launch_bounds__(256) void wprep1(
    const float* __restrict__ W1, const float* __restrict__ W2,
    const float* __restrict__ b1, const float* __restrict__ b2,
    const float* __restrict__ W13, const float* __restrict__ W23,
    const float* __restrict__ b13, const float* __restrict__ b23,
    float* __restrict__ scr)
{
    float* T1  = scr;            // [64][96]
    float* T3  = scr + 6144;     // [64][32]
    float* bt1 = scr + 8192;     // [96]
    float* bt3 = scr + 8288;     // [32]
    int i = blockIdx.x * 256 + threadIdx.x;
    if (i < 6144) {
        int r = i / 96, c = i % 96;
        float a = 0.f;
        #pragma unroll 8
        for (int k = 0; k < 32; ++k) a += W1[r * 32 + k] * W2[k * 96 + c];
        T1[i] = a;
    } else if ((i -= 6144) < 2048) {
        int r = i / 32, c = i % 32;
        float a = 0.f;
        #pragma unroll 8
        for (int k = 0; k < 32; ++k) a += W13[r * 32 + k] * W23[k * 32 + c];
        T3[i] = a;
    } else if ((i -= 2048) < 96) {
        float a = b2[i];
        #pragma unroll 8
        for (int k = 0; k < 32; ++k) a += b1[k] * W2[k * 96 + i];
        bt1[i] = a;
    } else if ((i -= 96) < 32) {
        float a = b23[i];
        #pragma unroll 8
        for (int k = 0; k < 32; ++k) a += b13[k] * W23[k * 32 + i];
        bt3[i] = a;
    }
}

// ---- wprep stage 2: fused bf16 tables; T1/T3/bt staged in LDS per block --
__global__ __launch_bounds__(256) void wprep2(
    const float* __restrict__ W3, const float* __restrict__ W33,
    const float* __restrict__ ii1, const float* __restrict__ ii3,
    const float* __restrict__ scr, u16* __restrict__ wb)
{
    __shared__ float sT1[6144];   // 24576 B
    __shared__ float sT3[2048];   // 8192 B
    __shared__ float sbt[128];    // bt1[96] | bt3[32]
    int tid = threadIdx.x;
    for (int i = tid; i < 6144; i += 256) sT1[i] = scr[i];
    for (int i = tid; i < 2048; i += 256) sT3[i] = scr[6144 + i];
    if (tid < 128) sbt[tid] = scr[8192 + tid];
    __syncthreads();

    int i0 = blockIdx.x * 256 + tid;
    if (i0 >= NWB) return;
    int i = i0;
    float v = 0.f;
    if (i < 49152) {            // WF1[b][nt][ks][L][j] = Wf1[k][c*8+b]
        int b = i / 6144, r = i % 6144;
        int nt = r / 1024, r2 = r % 1024;
        int ks = r2 / 512, r3 = r2 & 511;
        int L = r3 >> 3, j = r3 & 7;
        int k = ks * 32 + (L >> 4) * 8 + j;
        int c = 16 * nt + (L & 15);
        float a = 0.f;
        #pragma unroll 8
        for (int q = 0; q < 96; ++q) a += sT1[k * 96 + q] * W3[q * 768 + c * 8 + b];
        v = a;
    } else if ((i -= 49152) < 3072) {   // BB1[nt][L][j]
        int nt = i / 512, r3 = i & 511;
        int L = r3 >> 3, j = r3 & 7;
        if ((L >> 4) == 0) {
            int x = (16 * nt + (L & 15)) * 8 + j;
            float a = 0.f;
            #pragma unroll 8
            for (int q = 0; q < 96; ++q) a += sbt[q] * W3[q * 768 + x];
            v = a;
        }
    } else if ((i -= 3072) < 1024) {    // II1T[nt][L][j]
        int nt = i / 512, r3 = i & 511;
        int L = r3 >> 3, j = r3 & 7;
        v = ii1[((L >> 4) * 8 + j) * 32 + 16 * nt + (L & 15)];
    } else if ((i -= 1024) < 16384) {   // WF3[b][nt][ks][L][j]
        int b = i / 2048, r = i % 2048;
        int nt = r / 1024, r2 = r % 1024;
        int ks = r2 / 512, r3 = r2 & 511;
        int L = r3 >> 3, j = r3 & 7;
        int k = ks * 32 + (L >> 4) * 8 + j;
        int c = 16 * nt + (L & 15);
        float a = 0.f;
        #pragma unroll 8
        for (int q = 0; q < 32; ++q) a += sT3[k * 32 + q] * W33[q * 256 + c * 8 + b];
        v = a;
    } else if ((i -= 16384) < 1024) {   // BB3[nt][L][j]
        int nt = i / 512, r3 = i & 511;
        int L = r3 >> 3, j = r3 & 7;
        if ((L >> 4) == 0) {
            int x = (16 * nt + (L & 15)) * 8 + j;
            float a = 0.f;
            #pragma unroll 8
            for (int q = 0; q < 32; ++q) a += sbt[96 + q] * W33[q * 256 + x];
            v = a;
        }
    } else {                            // II3T[nt][L][j]
        i -= 1024;
        int nt = i / 512, r3 = i & 511;
        int L = r3 >> 3, j = r3 & 7;
        v = ii3[((L >> 4) * 8 + j) * 32 + 16 * nt + (L & 15)];
    }
    wb[i0] = (u16)f2b(v);
}

// ------- fused edge kernel: 32 edges per 1-wave block (2 M-tiles) ---------
// Round-15 edge kernel EXACTLY ((64,3): empirical VGPR cap ~85 on this
// toolchain fits the 80-VGPR wave program; (64,4) caps at 64 -> spills).
__global__ __launch_bounds__(64, 3) void edge_kernel(
    const u16* __restrict__ p1hb, const u16* __restrict__ p3hb,
    const float* __restrict__ r3, const float* __restrict__ basis,
    const int* __restrict__ idx_i, const int* __restrict__ idx_j,
    const u16* __restrict__ wb,
    const float* __restrict__ ii1b, const float* __restrict__ ii3b,
    float* __restrict__ p1n, float* __restrict__ p3n)
{
    // 3 KB LDS, single wave per block
    __shared__ int4 smem4[192];
    char* sw = (char*)smem4;
    int*   sIdxI = (int*)(sw + 0);       // [32]
    int*   sIdxJ = (int*)(sw + 128);     // [32]
    float* sBasT = (float*)(sw + 256);   // [8][32] transposed basis
    float* sR3   = (float*)(sw + 1280);  // [3][32]
    u16*   sT2   = (u16*)(sw + 1664);    // [16][40] transpose buffer

    const int l   = threadIdx.x & 63;
    const int r16 = l & 15;
    const int kg  = l >> 4;
    const int ebase = blockIdx.x * 32;

    // ---- staging (single wave: in-order LDS, no barriers) ----
    if (l < 32) sIdxI[l] = idx_i[ebase + l];
    else        sIdxJ[l - 32] = idx_j[ebase + l - 32];
    {
        int e = l & 31, hf = l >> 5;
        const float4* bp = (const float4*)(basis + (size_t)(ebase + e) * 8);
        float4 q = bp[hf];
        sBasT[(4 * hf + 0) * 32 + e] = q.x;
        sBasT[(4 * hf + 1) * 32 + e] = q.y;
        sBasT[(4 * hf + 2) * 32 + e] = q.z;
        sBasT[(4 * hf + 3) * 32 + e] = q.w;
        if (hf == 0) {
            sR3[e]      = r3[(size_t)(ebase + e) * 3 + 0];
            sR3[32 + e] = r3[(size_t)(ebase + e) * 3 + 1];
            sR3[64 + e] = r3[(size_t)(ebase + e) * 3 + 2];
        }
    }

    const float vii1[2] = { ii1b[r16], ii1b[16 + r16] };
    const float vii3[2] = { ii3b[r16], ii3b[16 + r16] };

    const f4v zf = {0.f, 0.f, 0.f, 0.f};

    // basis as K=8-padded A-fragment (for bias-init MFMAs)
    s8v bA[2];
    #pragma unroll
    for (int m = 0; m < 2; ++m) {
        s8v t;
        #pragma unroll
        for (int j = 0; j < 8; ++j)
            t[j] = (kg == 0) ? f2b(sBasT[j * 32 + m * 16 + r16]) : (short)0;
        bA[m] = t;
    }

    // ---- pi1: inter gathers (A-frags) ----
    s8v avI[2], avJ[2];
    #pragma unroll
    for (int m = 0; m < 2; ++m) {
        int rowA = m * 16 + r16;
        avI[m] = *(const s8v*)(p1hb + (size_t)sIdxI[rowA] * 32 + kg * 8);
        avJ[m] = *(const s8v*)(p1hb + (size_t)sIdxJ[rowA] * 32 + kg * 8);
    }

    // accT init = basis @ bf1  (bias term)
    f4v accT[2][6];
    {
        const u16* gBB = wb + OBB1;
        #pragma unroll
        for (int nt = 0; nt < 6; ++nt) {
            s8v bbv = *(const s8v*)(gBB + (nt * 64 + l) * 8);
            #pragma unroll
            for (int m = 0; m < 2; ++m)
                accT[m][nt] = __builtin_amdgcn_mfma_f32_16x16x32_bf16(bA[m], bbv, zf, 0, 0, 0);
        }
    }

    // ---- pi1 main: accT += basis_b * (inter @ Wf1_b) ----
    {
        const u16* gW = wb + OWF1;
        #pragma unroll 2
        for (int b = 0; b < 8; ++b) {
            float tb[2][4];
            #pragma unroll
            for (int m = 0; m < 2; ++m)
                #pragma unroll
                for (int rr = 0; rr < 4; ++rr)
                    tb[m][rr] = sBasT[b * 32 + m * 16 + 4 * kg + rr];
            #pragma unroll
            for (int nt = 0; nt < 6; ++nt) {
                const u16* bp = gW + ((size_t)(b * 6 + nt) * 2) * 512 + l * 8;
                s8v bv0 = *(const s8v*)(bp);
                s8v bv1 = *(const s8v*)(bp + 512);
                #pragma unroll
                for (int m = 0; m < 2; ++m) {
                    f4v D = __builtin_amdgcn_mfma_f32_16x16x32_bf16(avI[m], bv0, zf, 0, 0, 0);
                    D = __builtin_amdgcn_mfma_f32_16x16x32_bf16(avJ[m], bv1, D, 0, 0, 0);
                    #pragma unroll
                    for (int rr = 0; rr < 4; ++rr)
                        accT[m][nt][rr] += tb[m][rr] * D[rr];
                }
            }
        }
    }

    // ---- ii1: tanh(i1_1 @ ii1_W + b) -> atomic p1n[idx_j] ----
    {
        const u16* gII = wb + OII1T;
        #pragma unroll
        for (int m = 0; m < 2; ++m) {
            #pragma unroll
            for (int nt = 0; nt < 2; ++nt)
                #pragma unroll
                for (int rr = 0; rr < 4; ++rr)
                    sT2[(4 * kg + rr) * 40 + 16 * nt + r16] = (u16)f2b(accT[m][nt][rr]);
            s8v av = *(const s8v*)(sT2 + r16 * 40 + 8 * kg);
            #pragma unroll
            for (int nt = 0; nt < 2; ++nt) {
                s8v bv = *(const s8v*)(gII + (nt * 64 + l) * 8);
                f4v ia = __builtin_amdgcn_mfma_f32_16x16x32_bf16(av, bv, zf, 0, 0, 0);
                #pragma unroll
                for (int rr = 0; rr < 4; ++rr) {
                    int rowD = m * 16 + 4 * kg + rr;
                    atomicAdd(&p1n[(size_t)sIdxJ[rowD] * 32 + 16 * nt + r16],
                              tanhf_fast(ia[rr] + vii1[nt]));
                }
            }
        }
    }

    // ---- pi3 branch per Cartesian d ----
    const u16* gW3  = wb + OWF3;
    const u16* gBB3 = wb + OBB3;
    const u16* gII3 = wb + OII3T;
    for (int d = 0; d < 3; ++d) {
        s8v avI3[2], avJ3[2];
        #pragma unroll
        for (int m = 0; m < 2; ++m) {
            int rowA = m * 16 + r16;
            avI3[m] = *(const s8v*)(p3hb + ((size_t)sIdxI[rowA] * 3 + d) * 32 + kg * 8);
            avJ3[m] = *(const s8v*)(p3hb + ((size_t)sIdxJ[rowA] * 3 + d) * 32 + kg * 8);
        }
        f4v accP[2][2];
        #pragma unroll
        for (int nt = 0; nt < 2; ++nt) {
            s8v bbv = *(const s8v*)(gBB3 + (nt * 64 + l) * 8);
            #pragma unroll
            for (int m = 0; m < 2; ++m)
                accP[m][nt] = __builtin_amdgcn_mfma_f32_16x16x32_bf16(bA[m], bbv, zf, 0, 0, 0);
        }
        #pragma unroll 2
        for (int b = 0; b < 8; ++b) {
            float tb[2][4];
            #pragma unroll
            for (int m = 0; m < 2; ++m)
                #pragma unroll
                for (int rr = 0; rr < 4; ++rr)
                    tb[m][rr] = sBasT[b * 32 + m * 16 + 4 * kg + rr];
            #pragma unroll
            for (int nt = 0; nt < 2; ++nt) {
                const u16* bp = gW3 + ((size_t)(b * 2 + nt) * 2) * 512 + l * 8;
                s8v bv0 = *(const s8v*)(bp);
                s8v bv1 = *(const s8v*)(bp + 512);
                #pragma unroll
                for (int m = 0; m < 2; ++m) {
                    f4v D = __builtin_amdgcn_mfma_f32_16x16x32_bf16(avI3[m], bv0, zf, 0, 0, 0);
                    D = __builtin_amdgcn_mfma_f32_16x16x32_bf16(avJ3[m], bv1, D, 0, 0, 0);
                    #pragma unroll
                    for (int rr = 0; rr < 4; ++rr)
                        accP[m][nt][rr] += tb[m][rr] * D[rr];
                }
            }
        }
        // ii3 + combine + atomic p3n
        #pragma unroll
        for (int m = 0; m < 2; ++m) {
            #pragma unroll
            for (int nt = 0; nt < 2; ++nt)
                #pragma unroll
                for (int rr = 0; rr < 4; ++rr)
                    sT2[(4 * kg + rr) * 40 + 16 * nt + r16] = (u16)f2b(accP[m][nt][rr]);
            s8v av = *(const s8v*)(sT2 + r16 * 40 + 8 * kg);
            #pragma unroll
            for (int nt = 0; nt < 2; ++nt) {
                s8v bv = *(const s8v*)(gII3 + (nt * 64 + l) * 8);
                f4v ja = __builtin_amdgcn_mfma_f32_16x16x32_bf16(av, bv, zf, 0, 0, 0);
                #pragma unroll
                for (int rr = 0; rr < 4; ++rr) {
                    int rowD = m * 16 + 4 * kg + rr;
                    float i3a = tanhf_fast(ja[rr] + vii3[nt]);
                    float val = i3a * accT[m][2 + nt][rr] + sR3[d * 32 + rowD] * accT[m][4 + nt][rr];
                    atomicAdd(&p3n[((size_t)sIdxJ[rowD] * 3 + d) * 32 + 16 * nt + r16], val);
                }
            }
        }
    }
}

// ---------------- finalize: p1o = sum_d p3n^2 + p1n ; p3o = p3n * p1o -----
__global__ __launch_bounds__(256) void finalize_kernel(
    const float* __restrict__ p1n, const float* __restrict__ p3n,
    float* __restrict__ out)
{
    int t = blockIdx.x * 256 + threadIdx.x;
    int n = t >> 5, c = t & 31;
    float a0 = p3n[(n * 3 + 0) * 32 + c];
    float a1 = p3n[(n * 3 + 1) * 32 + c];
    float a2 = p3n[(n * 3 + 2) * 32 + c];
    float p1o = p1n[t] + a0 * a0 + a1 * a1 + a2 * a2;
    out[t] = p1o;
    float* o3 = out + NN * 32;
    o3[(n * 3 + 0) * 32 + c] = a0 * p1o;
    o3[(n * 3 + 1) * 32 + c] = a1 * p1o;
    o3[(n * 3 + 2) * 32 + c] = a2 * p1o;
}

extern "C" void kernel_launch(void* const* d_in, const int* in_sizes, int n_in,
                              void* d_out, int out_size, void* d_ws, size_t ws_size,
                              hipStream_t stream) {
    const float* p1     = (const float*)d_in[0];
    const float* p3     = (const float*)d_in[1];
    const float* r3     = (const float*)d_in[2];
    const float* basis  = (const float*)d_in[3];
    const int*   idx_i  = (const int*)d_in[4];
    const int*   idx_j  = (const int*)d_in[5];
    const float* pp1_W  = (const float*)d_in[6];
    const float* pp1_b  = (const float*)d_in[7];
    const float* pi1_W1 = (const float*)d_in[8];
    const float* pi1_b1 = (const float*)d_in[9];
    const float* pi1_W2 = (const float*)d_in[10];
    const float* pi1_b2 = (const float*)d_in[11];
    const float* pi1_W3 = (const float*)d_in[12];
    const float* ii1_W  = (const float*)d_in[13];
    const float* ii1_b  = (const float*)d_in[14];
    const float* pp3_W  = (const float*)d_in[15];
    const float* pp3_b  = (const float*)d_in[16];
    const float* pi3_W1 = (const float*)d_in[17];
    const float* pi3_b1 = (const float*)d_in[18];
    const float* pi3_W2 = (const float*)d_in[19];
    const float* pi3_b2 = (const float*)d_in[20];
    const float* pi3_W3 = (const float*)d_in[21];
    const float* ii3_W  = (const float*)d_in[22];
    const float* ii3_b  = (const float*)d_in[23];

    char* ws = (char*)d_ws;
    u16*   p1hb = (u16*)(ws + OFF_P1HB);
    u16*   p3hb = (u16*)(ws + OFF_P3HB);
    u16*   wb   = (u16*)(ws + OFF_WB);
    float* scr  = (float*)(ws + OFF_SCR);
    float* p1n  = (float*)(ws + OFF_P1N);
    float* p3n  = (float*)(ws + OFF_P3N);

    hipMemsetAsync(p1n, 0, 5120000, stream);

    node_prep<<<dim3(5000), dim3(256), 0, stream>>>(p1, p3, pp1_W, pp1_b, pp3_W, pp3_b, p1hb, p3hb);
    wprep1<<<dim3(33), dim3(256), 0, stream>>>(
        pi1_W1, pi1_W2, pi1_b1, pi1_b2, pi3_W1, pi3_W2, pi3_b1, pi3_b2, scr);
    wprep2<<<dim3((NWB + 255) / 256), dim3(256), 0, stream>>>(
        pi1_W3, pi3_W3, ii1_W, ii3_W, scr, wb);

    edge_kernel<<<dim3(NE / 32), dim3(64), 0, stream>>>(
        p1hb, p3hb, r3, basis, idx_i, idx_j, wb,
        ii1_b, ii3_b, p1n, p3n);

    finalize_kernel<<<dim3(1250), dim3(256), 0, stream>>>(p1n, p3n, (float*)d_out);
}

// Round 20
// 136.210 us; speedup vs baseline: 1.3147x; 1.0259x over previous
//
#include <hip/hip_runtime.h>
#include <math.h>

#define NN 10000
#define NE 160000

typedef __attribute__((ext_vector_type(8))) short s8v;
typedef __attribute__((ext_vector_type(4))) float f4v;
typedef unsigned short u16;

// ---- ws byte layout ----
#define OFF_P1HB 0u          // N*32 bf16      = 640000 B
#define OFF_P3HB 640000u     // N*3*32 bf16    = 1920000 B
#define OFF_WB   2560000u    // NWB u16        = 143360 B
#define OFF_SCR  2703360u    // 8320 f32 scratch (T1,T3,bt1,bt3) = 33280 B
#define OFF_P1N  2736640u    // N*32 f32       = 1280000 B
#define OFF_P3N  4016640u    // N*3*32 f32     = 3840000 B

// ---- wb (u16) offsets: fused weights, lane-consumption order [..][64][8] --
#define OWF1  0       // [b8][nt6][ks2][64][8] = 49152  (Wf1 = W1@W2@W3)
#define OBB1  49152   // [nt6][64][8]          = 3072   (bf1, k<8 else 0)
#define OII1T 52224   // [nt2][64][8]          = 1024
#define OWF3  53248   // [b8][nt2][ks2][64][8] = 16384  (Wf3 = W13@W23@W33)
#define OBB3  69632   // [nt2][64][8]          = 1024   (bf3)
#define OII3T 70656   // [nt2][64][8]          = 1024
#define NWB   71680

__device__ __forceinline__ short f2b(float f) {
    unsigned u = __float_as_uint(f);
    u += 0x7fffu + ((u >> 16) & 1u);
    return (short)(u >> 16);
}
__device__ __forceinline__ float tanhf_fast(float x) {
    float xc = fminf(9.f, fmaxf(-9.f, x));
    float e = __expf(2.f * xc);
    return (e - 1.f) * __builtin_amdgcn_rcpf(e + 1.f);
}

// ---------------- node prep: p1h/p3h = tanh(x@W+b) -> bf16 ----------------
__global__ __launch_bounds__(256) void node_prep(
    const float* __restrict__ p1, const float* __restrict__ p3,
    const float* __restrict__ pp1_W, const float* __restrict__ pp1_b,
    const float* __restrict__ pp3_W, const float* __restrict__ pp3_b,
    u16* __restrict__ p1hb, u16* __restrict__ p3hb)
{
    __shared__ float Ws[2][32 * 32];
    __shared__ float bsm[2][32];
    int tid = threadIdx.x;
    for (int i = tid; i < 32 * 32; i += 256) { Ws[0][i] = pp1_W[i]; Ws[1][i] = pp3_W[i]; }
    if (tid < 32) { bsm[0][tid] = pp1_b[tid]; bsm[1][tid] = pp3_b[tid]; }
    __syncthreads();
    int idx = blockIdx.x * 256 + tid;
    int n = idx >> 7;
    int r = (idx >> 5) & 3;
    int c = idx & 31;
    int sel = (r == 0) ? 0 : 1;
    const float* in = (r == 0) ? (p1 + n * 32) : (p3 + (n * 3 + (r - 1)) * 32);
    float acc = bsm[sel][c];
    #pragma unroll
    for (int k = 0; k < 32; ++k) acc += in[k] * Ws[sel][k * 32 + c];
    short v = f2b(tanhf(acc));
    if (r == 0) p1hb[n * 32 + c] = (u16)v;
    else        p3hb[(n * 3 + (r - 1)) * 32 + c] = (u16)v;
}

// ---- wprep stage 1 (4-lane cooperative): T1 = W1@W2, T3 = W13@W23,
//      bt1 = b1@W2 + b2, bt3 = b13@W23 + b23  (all f32) -------------------
__global__ __launch_bounds__(256) void wprep1(
    const float* __restrict__ W1, const float* __restrict__ W2,
    const float* __restrict__ b1, const float* __restrict__ b2,
    const float* __restrict__ W13, const float* __restrict__ W23,
    const float* __restrict__ b13, const float* __restrict__ b23,
    float* __restrict__ scr)
{
    int gt = blockIdx.x * 256 + threadIdx.x;     // 33280 threads
    int i0 = gt >> 2, sub = gt & 3;
    if (i0 >= 8320) return;
    int i = i0;
    float a = 0.f;
    int k0 = sub * 8;
    if (i < 6144) {
        int r = i / 96, c = i % 96;
        #pragma unroll
        for (int k = k0; k < k0 + 8; ++k) a += W1[r * 32 + k] * W2[k * 96 + c];
    } else if ((i -= 6144) < 2048) {
        int r = i / 32, c = i % 32;
        #pragma unroll
        for (int k = k0; k < k0 + 8; ++k) a += W13[r * 32 + k] * W23[k * 32 + c];
    } else if ((i -= 2048) < 96) {
        if (sub == 0) a = b2[i];
        #pragma unroll
        for (int k = k0; k < k0 + 8; ++k) a += b1[k] * W2[k * 96 + i];
    } else {
        i -= 96;
        if (sub == 0) a = b23[i];
        #pragma unroll
        for (int k = k0; k < k0 + 8; ++k) a += b13[k] * W23[k * 32 + i];
    }
    a += __shfl_xor(a, 1);
    a += __shfl_xor(a, 2);
    if (sub == 0) scr[i0] = a;
}

// ---- wprep stage 2 (4-lane cooperative): fused bf16 tables ----------------
__global__ __launch_bounds__(256) void wprep2(
    const float* __restrict__ W3, const float* __restrict__ W33,
    const float* __restrict__ ii1, const float* __restrict__ ii3,
    const float* __restrict__ scr, u16* __restrict__ wb)
{
    int gt = blockIdx.x * 256 + threadIdx.x;     // 286720 threads = 4*NWB
    int i0 = gt >> 2, sub = gt & 3;
    int i = i0;
    float a = 0.f;
    if (i < 49152) {            // WF1[b][nt][ks][L][j] = Wf1[k][c*8+b], K=96
        int b = i / 6144, r = i % 6144;
        int nt = r / 1024, r2 = r % 1024;
        int ks = r2 / 512, r3 = r2 & 511;
        int L = r3 >> 3, j = r3 & 7;
        int k = ks * 32 + (L >> 4) * 8 + j;
        int c = 16 * nt + (L & 15);
        int q0 = sub * 24;
        #pragma unroll 8
        for (int q = q0; q < q0 + 24; ++q)
            a += scr[k * 96 + q] * W3[q * 768 + c * 8 + b];
    } else if ((i -= 49152) < 3072) {   // BB1[nt][L][j], K=96
        int nt = i / 512, r3 = i & 511;
        int L = r3 >> 3, j = r3 & 7;
        if ((L >> 4) == 0) {
            int x = (16 * nt + (L & 15)) * 8 + j;
            int q0 = sub * 24;
            #pragma unroll 8
            for (int q = q0; q < q0 + 24; ++q)
                a += scr[8192 + q] * W3[q * 768 + x];
        }
    } else if ((i -= 3072) < 1024) {    // II1T[nt][L][j]  (copy)
        if (sub == 0) {
            int nt = i / 512, r3 = i & 511;
            int L = r3 >> 3, j = r3 & 7;
            a = ii1[((L >> 4) * 8 + j) * 32 + 16 * nt + (L & 15)];
        }
    } else if ((i -= 1024) < 16384) {   // WF3[b][nt][ks][L][j], K=32
        int b = i / 2048, r = i % 2048;
        int nt = r / 1024, r2 = r % 1024;
        int ks = r2 / 512, r3 = r2 & 511;
        int L = r3 >> 3, j = r3 & 7;
        int k = ks * 32 + (L >> 4) * 8 + j;
        int c = 16 * nt + (L & 15);
        int q0 = sub * 8;
        #pragma unroll
        for (int q = q0; q < q0 + 8; ++q)
            a += scr[6144 + k * 32 + q] * W33[q * 256 + c * 8 + b];
    } else if ((i -= 16384) < 1024) {   // BB3[nt][L][j], K=32
        int nt = i / 512, r3 = i & 511;
        int L = r3 >> 3, j = r3 & 7;
        if ((L >> 4) == 0) {
            int x = (16 * nt + (L & 15)) * 8 + j;
            int q0 = sub * 8;
            #pragma unroll
            for (int q = q0; q < q0 + 8; ++q)
                a += scr[8288 + q] * W33[q * 256 + x];
        }
    } else {                            // II3T[nt][L][j]  (copy)
        if (sub == 0) {
            i -= 1024;
            int nt = i / 512, r3 = i & 511;
            int L = r3 >> 3, j = r3 & 7;
            a = ii3[((L >> 4) * 8 + j) * 32 + 16 * nt + (L & 15)];
        }
    }
    a += __shfl_xor(a, 1);
    a += __shfl_xor(a, 2);
    if (sub == 0) wb[i0] = (u16)f2b(a);
}

// ------- fused edge kernel: 32 edges per 1-wave block (2 M-tiles) ---------
// Round-15/19 edge kernel EXACTLY ((64,3): empirical VGPR cap ~85 fits the
// 80-VGPR wave program; (64,4) caps at 64 -> spills). Measured ~107 us.
__global__ __launch_bounds__(64, 3) void edge_kernel(
    const u16* __restrict__ p1hb, const u16* __restrict__ p3hb,
    const float* __restrict__ r3, const float* __restrict__ basis,
    const int* __restrict__ idx_i, const int* __restrict__ idx_j,
    const u16* __restrict__ wb,
    const float* __restrict__ ii1b, const float* __restrict__ ii3b,
    float* __restrict__ p1n, float* __restrict__ p3n)
{
    // 3 KB LDS, single wave per block
    __shared__ int4 smem4[192];
    char* sw = (char*)smem4;
    int*   sIdxI = (int*)(sw + 0);       // [32]
    int*   sIdxJ = (int*)(sw + 128);     // [32]
    float* sBasT = (float*)(sw + 256);   // [8][32] transposed basis
    float* sR3   = (float*)(sw + 1280);  // [3][32]
    u16*   sT2   = (u16*)(sw + 1664);    // [16][40] transpose buffer

    const int l   = threadIdx.x & 63;
    const int r16 = l & 15;
    const int kg  = l >> 4;
    const int ebase = blockIdx.x * 32;

    // ---- staging (single wave: in-order LDS, no barriers) ----
    if (l < 32) sIdxI[l] = idx_i[ebase + l];
    else        sIdxJ[l - 32] = idx_j[ebase + l - 32];
    {
        int e = l & 31, hf = l >> 5;
        const float4* bp = (const float4*)(basis + (size_t)(ebase + e) * 8);
        float4 q = bp[hf];
        sBasT[(4 * hf + 0) * 32 + e] = q.x;
        sBasT[(4 * hf + 1) * 32 + e] = q.y;
        sBasT[(4 * hf + 2) * 32 + e] = q.z;
        sBasT[(4 * hf + 3) * 32 + e] = q.w;
        if (hf == 0) {
            sR3[e]      = r3[(size_t)(ebase + e) * 3 + 0];
            sR3[32 + e] = r3[(size_t)(ebase + e) * 3 + 1];
            sR3[64 + e] = r3[(size_t)(ebase + e) * 3 + 2];
        }
    }

    const float vii1[2] = { ii1b[r16], ii1b[16 + r16] };
    const float vii3[2] = { ii3b[r16], ii3b[16 + r16] };

    const f4v zf = {0.f, 0.f, 0.f, 0.f};

    // basis as K=8-padded A-fragment (for bias-init MFMAs)
    s8v bA[2];
    #pragma unroll
    for (int m = 0; m < 2; ++m) {
        s8v t;
        #pragma unroll
        for (int j = 0; j < 8; ++j)
            t[j] = (kg == 0) ? f2b(sBasT[j * 32 + m * 16 + r16]) : (short)0;
        bA[m] = t;
    }

    // ---- pi1: inter gathers (A-frags) ----
    s8v avI[2], avJ[2];
    #pragma unroll
    for (int m = 0; m < 2; ++m) {
        int rowA = m * 16 + r16;
        avI[m] = *(const s8v*)(p1hb + (size_t)sIdxI[rowA] * 32 + kg * 8);
        avJ[m] = *(const s8v*)(p1hb + (size_t)sIdxJ[rowA] * 32 + kg * 8);
    }

    // accT init = basis @ bf1  (bias term)
    f4v accT[2][6];
    {
        const u16* gBB = wb + OBB1;
        #pragma unroll
        for (int nt = 0; nt < 6; ++nt) {
            s8v bbv = *(const s8v*)(gBB + (nt * 64 + l) * 8);
            #pragma unroll
            for (int m = 0; m < 2; ++m)
                accT[m][nt] = __builtin_amdgcn_mfma_f32_16x16x32_bf16(bA[m], bbv, zf, 0, 0, 0);
        }
    }

    // ---- pi1 main: accT += basis_b * (inter @ Wf1_b) ----
    {
        const u16* gW = wb + OWF1;
        #pragma unroll 2
        for (int b = 0; b < 8; ++b) {
            float tb[2][4];
            #pragma unroll
            for (int m = 0; m < 2; ++m)
                #pragma unroll
                for (int rr = 0; rr < 4; ++rr)
                    tb[m][rr] = sBasT[b * 32 + m * 16 + 4 * kg + rr];
            #pragma unroll
            for (int nt = 0; nt < 6; ++nt) {
                const u16* bp = gW + ((size_t)(b * 6 + nt) * 2) * 512 + l * 8;
                s8v bv0 = *(const s8v*)(bp);
                s8v bv1 = *(const s8v*)(bp + 512);
                #pragma unroll
                for (int m = 0; m < 2; ++m) {
                    f4v D = __builtin_amdgcn_mfma_f32_16x16x32_bf16(avI[m], bv0, zf, 0, 0, 0);
                    D = __builtin_amdgcn_mfma_f32_16x16x32_bf16(avJ[m], bv1, D, 0, 0, 0);
                    #pragma unroll
                    for (int rr = 0; rr < 4; ++rr)
                        accT[m][nt][rr] += tb[m][rr] * D[rr];
                }
            }
        }
    }

    // ---- ii1: tanh(i1_1 @ ii1_W + b) -> atomic p1n[idx_j] ----
    {
        const u16* gII = wb + OII1T;
        #pragma unroll
        for (int m = 0; m < 2; ++m) {
            #pragma unroll
            for (int nt = 0; nt < 2; ++nt)
                #pragma unroll
                for (int rr = 0; rr < 4; ++rr)
                    sT2[(4 * kg + rr) * 40 + 16 * nt + r16] = (u16)f2b(accT[m][nt][rr]);
            s8v av = *(const s8v*)(sT2 + r16 * 40 + 8 * kg);
            #pragma unroll
            for (int nt = 0; nt < 2; ++nt) {
                s8v bv = *(const s8v*)(gII + (nt * 64 + l) * 8);
                f4v ia = __builtin_amdgcn_mfma_f32_16x16x32_bf16(av, bv, zf, 0, 0, 0);
                #pragma unroll
                for (int rr = 0; rr < 4; ++rr) {
                    int rowD = m * 16 + 4 * kg + rr;
                    atomicAdd(&p1n[(size_t)sIdxJ[rowD] * 32 + 16 * nt + r16],
                              tanhf_fast(ia[rr] + vii1[nt]));
                }
            }
        }
    }

    // ---- pi3 branch per Cartesian d ----
    const u16* gW3  = wb + OWF3;
    const u16* gBB3 = wb + OBB3;
    const u16* gII3 = wb + OII3T;
    for (int d = 0; d < 3; ++d) {
        s8v avI3[2], avJ3[2];
        #pragma unroll
        for (int m = 0; m < 2; ++m) {
            int rowA = m * 16 + r16;
            avI3[m] = *(const s8v*)(p3hb + ((size_t)sIdxI[rowA] * 3 + d) * 32 + kg * 8);
            avJ3[m] = *(const s8v*)(p3hb + ((size_t)sIdxJ[rowA] * 3 + d) * 32 + kg * 8);
        }
        f4v accP[2][2];
        #pragma unroll
        for (int nt = 0; nt < 2; ++nt) {
            s8v bbv = *(const s8v*)(gBB3 + (nt * 64 + l) * 8);
            #pragma unroll
            for (int m = 0; m < 2; ++m)
                accP[m][nt] = __builtin_amdgcn_mfma_f32_16x16x32_bf16(bA[m], bbv, zf, 0, 0, 0);
        }
        #pragma unroll 2
        for (int b = 0; b < 8; ++b) {
            float tb[2][4];
            #pragma unroll
            for (int m = 0; m < 2; ++m)
                #pragma unroll
                for (int rr = 0; rr < 4; ++rr)
                    tb[m][rr] = sBasT[b * 32 + m * 16 + 4 * kg + rr];
            #pragma unroll
            for (int nt = 0; nt < 2; ++nt) {
                const u16* bp = gW3 + ((size_t)(b * 2 + nt) * 2) * 512 + l * 8;
                s8v bv0 = *(const s8v*)(bp);
                s8v bv1 = *(const s8v*)(bp + 512);
                #pragma unroll
                for (int m = 0; m < 2; ++m) {
                    f4v D = __builtin_amdgcn_mfma_f32_16x16x32_bf16(avI3[m], bv0, zf, 0, 0, 0);
                    D = __builtin_amdgcn_mfma_f32_16x16x32_bf16(avJ3[m], bv1, D, 0, 0, 0);
                    #pragma unroll
                    for (int rr = 0; rr < 4; ++rr)
                        accP[m][nt][rr] += tb[m][rr] * D[rr];
                }
            }
        }
        // ii3 + combine + atomic p3n
        #pragma unroll
        for (int m = 0; m < 2; ++m) {
            #pragma unroll
            for (int nt = 0; nt < 2; ++nt)
                #pragma unroll
                for (int rr = 0; rr < 4; ++rr)
                    sT2[(4 * kg + rr) * 40 + 16 * nt + r16] = (u16)f2b(accP[m][nt][rr]);
            s8v av = *(const s8v*)(sT2 + r16 * 40 + 8 * kg);
            #pragma unroll
            for (int nt = 0; nt < 2; ++nt) {
                s8v bv = *(const s8v*)(gII3 + (nt * 64 + l) * 8);
                f4v ja = __builtin_amdgcn_mfma_f32_16x16x32_bf16(av, bv, zf, 0, 0, 0);
                #pragma unroll
                for (int rr = 0; rr < 4; ++rr) {
                    int rowD = m * 16 + 4 * kg + rr;
                    float i3a = tanhf_fast(ja[rr] + vii3[nt]);
                    float val = i3a * accT[m][2 + nt][rr] + sR3[d * 32 + rowD] * accT[m][4 + nt][rr];
                    atomicAdd(&p3n[((size_t)sIdxJ[rowD] * 3 + d) * 32 + 16 * nt + r16], val);
                }
            }
        }
    }
}

// ---------------- finalize: p1o = sum_d p3n^2 + p1n ; p3o = p3n * p1o -----
__global__ __launch_bounds__(256) void finalize_kernel(
    const float* __restrict__ p1n, const float* __restrict__ p3n,
    float* __restrict__ out)
{
    int t = blockIdx.x * 256 + threadIdx.x;
    int n = t >> 5, c = t & 31;
    float a0 = p3n[(n * 3 + 0) * 32 + c];
    float a1 = p3n[(n * 3 + 1) * 32 + c];
    float a2 = p3n[(n * 3 + 2) * 32 + c];
    float p1o = p1n[t] + a0 * a0 + a1 * a1 + a2 * a2;
    out[t] = p1o;
    float* o3 = out + NN * 32;
    o3[(n * 3 + 0) * 32 + c] = a0 * p1o;
    o3[(n * 3 + 1) * 32 + c] = a1 * p1o;
    o3[(n * 3 + 2) * 32 + c] = a2 * p1o;
}

extern "C" void kernel_launch(void* const* d_in, const int* in_sizes, int n_in,
                              void* d_out, int out_size, void* d_ws, size_t ws_size,
                              hipStream_t stream) {
    const float* p1     = (const float*)d_in[0];
    const float* p3     = (const float*)d_in[1];
    const float* r3     = (const float*)d_in[2];
    const float* basis  = (const float*)d_in[3];
    const int*   idx_i  = (const int*)d_in[4];
    const int*   idx_j  = (const int*)d_in[5];
    const float* pp1_W  = (const float*)d_in[6];
    const float* pp1_b  = (const float*)d_in[7];
    const float* pi1_W1 = (const float*)d_in[8];
    const float* pi1_b1 = (const float*)d_in[9];
    const float* pi1_W2 = (const float*)d_in[10];
    const float* pi1_b2 = (const float*)d_in[11];
    const float* pi1_W3 = (const float*)d_in[12];
    const float* ii1_W  = (const float*)d_in[13];
    const float* ii1_b  = (const float*)d_in[14];
    const float* pp3_W  = (const float*)d_in[15];
    const float* pp3_b  = (const float*)d_in[16];
    const float* pi3_W1 = (const float*)d_in[17];
    const float* pi3_b1 = (const float*)d_in[18];
    const float* pi3_W2 = (const float*)d_in[19];
    const float* pi3_b2 = (const float*)d_in[20];
    const float* pi3_W3 = (const float*)d_in[21];
    const float* ii3_W  = (const float*)d_in[22];
    const float* ii3_b  = (const float*)d_in[23];

    char* ws = (char*)d_ws;
    u16*   p1hb = (u16*)(ws + OFF_P1HB);
    u16*   p3hb = (u16*)(ws + OFF_P3HB);
    u16*   wb   = (u16*)(ws + OFF_WB);
    float* scr  = (float*)(ws + OFF_SCR);
    float* p1n  = (float*)(ws + OFF_P1N);
    float* p3n  = (float*)(ws + OFF_P3N);

    hipMemsetAsync(p1n, 0, 5120000, stream);

    node_prep<<<dim3(5000), dim3(256), 0, stream>>>(p1, p3, pp1_W, pp1_b, pp3_W, pp3_b, p1hb, p3hb);
    wprep1<<<dim3(130), dim3(256), 0, stream>>>(
        pi1_W1, pi1_W2, pi1_b1, pi1_b2, pi3_W1, pi3_W2, pi3_b1, pi3_b2, scr);
    wprep2<<<dim3(1120), dim3(256), 0, stream>>>(
        pi1_W3, pi3_W3, ii1_W, ii3_W, scr, wb);

    edge_kernel<<<dim3(NE / 32), dim3(64), 0, stream>>>(
        p1hb, p3hb, r3, basis, idx_i, idx_j, wb,
        ii1_b, ii3_b, p1n, p3n);

    finalize_kernel<<<dim3(1250), dim3(256), 0, stream>>>(p1n, p3n, (float*)d_out);
}